// Round 4
// baseline (411.206 us; speedup 1.0000x reference)
//
#include <hip/hip_runtime.h>
#include <cstdint>
#include <cstddef>

typedef unsigned short u16;
typedef __attribute__((ext_vector_type(8))) short s16x8;      // 8 bf16 = 4 VGPRs (MFMA A/B frag)
typedef __attribute__((ext_vector_type(8))) unsigned short u16x8;
typedef __attribute__((ext_vector_type(4))) unsigned short u16x4;
typedef __attribute__((ext_vector_type(4))) float f32x4;      // MFMA C/D frag / float4 load

#define D_MODEL 1024
#define DH 64
#define BS 256
// B*S = 16384 tokens, 64 blocks of 256, 16 heads. External tensors are FLOAT32; internal bf16.

__device__ __forceinline__ u16 f2bf(float f) {
  union { float f; unsigned int i; } x; x.f = f;
  unsigned int r = x.i + 0x7fffu + ((x.i >> 16) & 1u);   // RNE
  return (u16)(r >> 16);
}

__device__ __forceinline__ void gl_lds16(const u16* g, u16* l) {
  __builtin_amdgcn_global_load_lds((const __attribute__((address_space(1))) void*)g,
                                   (__attribute__((address_space(3))) void*)l, 16, 0, 0);
}

__device__ __forceinline__ unsigned lds_off(const u16* p) {
  return (unsigned)(uintptr_t)(const __attribute__((address_space(3))) u16*)p;
}

// ---------------- cast x: f32 -> bf16, 16.7M elems ----------------
__global__ __launch_bounds__(256) void cast_x(const float* __restrict__ x, u16* __restrict__ xb) {
  int i = (blockIdx.x * 256 + threadIdx.x) * 8;
  f32x4 a0 = *(const f32x4*)(x + i);
  f32x4 a1 = *(const f32x4*)(x + i + 4);
  u16x8 v;
#pragma unroll
  for (int j = 0; j < 4; ++j) { v[j] = f2bf(a0[j]); v[j + 4] = f2bf(a1[j]); }
  *(u16x8*)(xb + i) = v;
}

// ---------------- W transpose+cast: Wt[n][k] = bf16(W[k][n]) (1024x1024 f32 -> bf16, x4) ----------------
__global__ __launch_bounds__(256) void transpose_w(const float* __restrict__ w0,
                                                   const float* __restrict__ w1,
                                                   const float* __restrict__ w2,
                                                   const float* __restrict__ w3,
                                                   u16* __restrict__ out) {
  __shared__ u16 tile[64][65];
  const int z = blockIdx.z;
  const float* W = (z == 0) ? w0 : (z == 1) ? w1 : (z == 2) ? w2 : w3;
  u16* O = out + (size_t)z * (D_MODEL * D_MODEL);
  const int kb = blockIdx.y * 64, nb = blockIdx.x * 64;
  const int t = threadIdx.x;
#pragma unroll
  for (int i = 0; i < 16; ++i) {
    int e = i * 256 + t;
    int r = e >> 6, c = e & 63;
    tile[r][c] = f2bf(W[(size_t)(kb + r) * D_MODEL + nb + c]);
  }
  __syncthreads();
#pragma unroll
  for (int i = 0; i < 16; ++i) {
    int e = i * 256 + t;
    int r = e >> 6, c = e & 63;
    O[(size_t)(nb + r) * D_MODEL + kb + c] = tile[c][r];
  }
}

// ================= 256x256 8-phase GEMM (m201 template, plain HIP + asm ds_read) =================
// BM=BN=256, BK=64, 512 threads = 8 waves (2M x 4N), per-wave C = 128x64.
// LDS 128 KiB: As[2][256][64], Bs[2][256][64] bf16, double-buffered.
// T2 swizzle (FULL): byte ^= ((row&7)<<4) — 16 aliasing rows spread over all 8 16B slots
// (2 rows/slot = 2-way = free, m136). Both-sides (rule #21): linear gl_lds DEST +
// inverse-permuted global SOURCE chunk (c ^ ((c>>3)&7)) + swizzled ds_read column.
// T4 (counted vmcnt) requires asm ds_read (invisible to alias analysis) + rule #18 fences.
// V plane (z==2) epilogue writes V^T [n][h][d][tok] so attn needs no LDS V staging (R3).

#define TIU 16384   // u16 per 256x64 buffer
#define HIU 8192    // u16 per 128x64 half-tile

__device__ __forceinline__ void stage_half(const u16* __restrict__ src, int rowG0, int k0,
                                           u16* ldst, int tid) {
#pragma unroll
  for (int i = 0; i < 2; ++i) {
    int c = i * 512 + tid;                       // linear 16B chunk in half-tile
    int cs = c ^ ((c >> 3) & 7);                 // inverse (row&7)<<4 swizzle (involution)
    gl_lds16(src + (size_t)(rowG0 + (cs >> 3)) * D_MODEL + k0 + (cs & 7) * 8,
             ldst + c * 8);
  }
}

#define NOPX ((void)0)
#define BARX() __builtin_amdgcn_s_barrier()
#define VMW(N) asm volatile("s_waitcnt vmcnt(" #N ")" ::: "memory")
#define SBAR() __builtin_amdgcn_sched_barrier(0)
#define LGK8() asm volatile("s_waitcnt lgkmcnt(8)")

// asm ds_read_b128: base VGPR (byte addr in LDS) + literal offset
#define DSR128(dst, b, off) asm volatile("ds_read_b128 %0, %1 offset:" #off : "=v"(dst) : "v"(b))

// A frags for half MH: rows arow + MH*64 + mt*16 (row&7 == l15&7, invariant under offsets).
// kk=0 via aK0 base, kk=1 via aK1 = aK0 ^ 64. Row steps (mt*16 rows = 2048 B) are literals.
#define LDA8(P, MH) do { \
  const unsigned _o = (P) * 32768u + (MH) * 8192u; \
  DSR128(a[0][0], aK0 + _o, 0);    DSR128(a[0][1], aK1 + _o, 0); \
  DSR128(a[1][0], aK0 + _o, 2048); DSR128(a[1][1], aK1 + _o, 2048); \
  DSR128(a[2][0], aK0 + _o, 4096); DSR128(a[2][1], aK1 + _o, 4096); \
  DSR128(a[3][0], aK0 + _o, 6144); DSR128(a[3][1], aK1 + _o, 6144); \
} while (0)

#define LDB4(P, NH) do { \
  const unsigned _o = (P) * 32768u + (NH) * 4096u; \
  DSR128(b[NH][0][0], bK0 + _o, 0);    DSR128(b[NH][0][1], bK1 + _o, 0); \
  DSR128(b[NH][1][0], bK0 + _o, 2048); DSR128(b[NH][1][1], bK1 + _o, 2048); \
} while (0)

#define MF16(MH, NH) do { \
  __builtin_amdgcn_s_setprio(1); \
  _Pragma("unroll") for (int kk = 0; kk < 2; ++kk) \
  _Pragma("unroll") for (int mt = 0; mt < 4; ++mt) \
  _Pragma("unroll") for (int nt = 0; nt < 2; ++nt) \
    acc[(MH) * 4 + mt][(NH) * 2 + nt] = __builtin_amdgcn_mfma_f32_16x16x32_bf16( \
        a[mt][kk], b[NH][nt][kk], acc[(MH) * 4 + mt][(NH) * 2 + nt], 0, 0, 0); \
  __builtin_amdgcn_s_setprio(0); \
} while (0)

#define STA(T, H) stage_half(A, rowBase + (H) * 128, (T) * 64, As + ((T) & 1) * TIU + (H) * HIU, t)
#define STB(T, H) stage_half(W, colBase + (H) * 128, (T) * 64, Bs + ((T) & 1) * TIU + (H) * HIU, t)

// barrier -> drain LDS reads -> pin scheduler -> MFMA
#define PWAIT() do { BARX(); asm volatile("s_waitcnt lgkmcnt(0)"); SBAR(); } while (0)

// One K-tile = 4 phases; quadrant order (0,0),(0,1),(1,1),(1,0): B halves reload once, A once.
// Phase 1 issues 12 ds_reads -> lgkmcnt(8) pacing before the barrier (m201 optional clause).
#define KTILE(P, S1, S2, S3, S4, WAIT) do { \
  LDA8(P, 0); LDB4(P, 0); S1; LGK8(); PWAIT();  MF16(0, 0); BARX(); \
  LDB4(P, 1);             S2; PWAIT();          MF16(0, 1); BARX(); \
  LDA8(P, 1);             S3; PWAIT();          MF16(1, 1); BARX(); \
                    S4; WAIT; BARX(); SBAR();   MF16(1, 0); BARX(); \
} while (0)

// MODE 0: fused QKV (bf16 out; Q,K linear, V transposed [n][h][d][tok]). MODE 1: O-proj (f32).
template <int MODE, int NCB>
__global__ __launch_bounds__(512, 2) void gemm8(
    const u16* __restrict__ A, const u16* __restrict__ W,
    const float* __restrict__ b0, const float* __restrict__ b1, const float* __restrict__ b2,
    void* __restrict__ o0, void* __restrict__ o1, void* __restrict__ o2) {
  __shared__ u16 As[2 * TIU];
  __shared__ u16 Bs[2 * TIU];

  // bijective XCD swizzle (nwg % 8 == 0 by construction: 768 / 256)
  const int nwg = gridDim.x;
  const int wg = blockIdx.x;
  const int swz = (wg & 7) * (nwg >> 3) + (wg >> 3);
  const int rowBase = (swz / NCB) * 256;
  const int colBase = (swz % NCB) * 256;

  const int t = threadIdx.x;
  const int wave = t >> 6, lane = t & 63, l15 = lane & 15, q4 = lane >> 4;
  const int wm = wave >> 2, wn = wave & 3;
  const int arow = wm * 128 + l15;
  const int brow = wn * 64 + l15;

  // LDS byte bases for asm ds_read (kk=0 / kk=1), swizzled column = (q4 ^ (l15&7)) << 4
  const unsigned swzc = (unsigned)((q4 ^ (l15 & 7)) << 4);
  const unsigned aK0 = lds_off(As) + (unsigned)arow * 128u + swzc;
  const unsigned aK1 = aK0 ^ 64u;
  const unsigned bK0 = lds_off(Bs) + (unsigned)brow * 128u + swzc;
  const unsigned bK1 = bK0 ^ 64u;

  f32x4 acc[8][4];
#pragma unroll
  for (int i = 0; i < 8; ++i)
#pragma unroll
    for (int j = 0; j < 4; ++j) acc[i][j] = {0.f, 0.f, 0.f, 0.f};

  s16x8 a[4][2];        // A frags: 4 m-tiles x 2 kk for current half
  s16x8 b[2][2][2];     // B frags: [nh][nt][kk], both halves live

  // Prologue: tile0 fully + 3 half-tiles of tile1 (issue order B0,B1,A0,A1 | B0,B1,A0)
  STB(0, 0); STB(0, 1); STA(0, 0); STA(0, 1);
  VMW(4);
  STB(1, 0); STB(1, 1); STA(1, 0);
  VMW(6);
  BARX();

#pragma unroll 1
  for (int tg = 0; tg < 14; tg += 2) {
    KTILE(0, STA(tg + 1, 1), STB(tg + 2, 0), STB(tg + 2, 1), STA(tg + 2, 0), VMW(6));
    KTILE(1, STA(tg + 2, 1), STB(tg + 3, 0), STB(tg + 3, 1), STA(tg + 3, 0), VMW(6));
  }
  // Tail: tile 14 finishes tile15's staging then drains; tile 15 computes only.
  KTILE(0, STA(15, 1), NOPX, NOPX, NOPX, VMW(0));
  KTILE(1, NOPX, NOPX, NOPX, NOPX, NOPX);

  // Epilogue: C/D map col = l15, row = q4*4 + r. ni INNERMOST so each row's 128B
  // line (64 cols x 2B) is written back-to-back -> no partial-line HBM double-write.
  if constexpr (MODE == 0) {
    const int z = colBase >> 10;                 // whole block is one z-plane (256 | 1024)
    const int colL = (colBase & 1023) + wn * 64;
    if (z < 2) {
      const float* bias = (z == 0) ? b0 : b1;
      u16* Out = (u16*)((z == 0) ? o0 : o1);
      float bv[4];
#pragma unroll
      for (int ni = 0; ni < 4; ++ni) bv[ni] = bias[colL + ni * 16 + l15];
#pragma unroll
      for (int mi = 0; mi < 8; ++mi) {
#pragma unroll
        for (int r = 0; r < 4; ++r) {
          size_t row = (size_t)(rowBase + wm * 128 + mi * 16 + q4 * 4 + r);
#pragma unroll
          for (int ni = 0; ni < 4; ++ni)
            Out[row * D_MODEL + colL + ni * 16 + l15] = f2bf(acc[mi][ni][r] + bv[ni]);
        }
      }
    } else {
      // V^T: Vt[((n*16+h)*64 + d)*256 + tok]; tok = rowBase..rowBase+255 (n = rowBase>>8),
      // d = (col&63), h = col>>6. Per lane: 4 consecutive tok -> one 8B u16x4 store.
      u16* Vt = (u16*)o2;
      const int nIdx = rowBase >> 8;
      float bv[4];
#pragma unroll
      for (int ni = 0; ni < 4; ++ni) bv[ni] = b2[colL + ni * 16 + l15];
#pragma unroll
      for (int mi = 0; mi < 8; ++mi) {
        const int tk = wm * 128 + mi * 16 + q4 * 4;
#pragma unroll
        for (int ni = 0; ni < 4; ++ni) {
          const int col = colL + ni * 16 + l15;
          u16x4 v4;
#pragma unroll
          for (int r = 0; r < 4; ++r) v4[r] = f2bf(acc[mi][ni][r] + bv[ni]);
          *(u16x4*)(Vt + (((size_t)nIdx * 16 + (col >> 6)) * 64 + (col & 63)) * 256 + tk) = v4;
        }
      }
    }
  } else {
    float* Out = (float*)o0;
    const int colL = colBase + wn * 64;
    float bv[4];
#pragma unroll
    for (int ni = 0; ni < 4; ++ni) bv[ni] = b0[colL + ni * 16 + l15];
#pragma unroll
    for (int mi = 0; mi < 8; ++mi) {
#pragma unroll
      for (int r = 0; r < 4; ++r) {
        size_t row = (size_t)(rowBase + wm * 128 + mi * 16 + q4 * 4 + r);
#pragma unroll
        for (int ni = 0; ni < 4; ++ni)
          Out[row * D_MODEL + colL + ni * 16 + l15] = acc[mi][ni][r] + bv[ni];
      }
    }
  }
}

// ---------------- Attention (R3 restructure): 4 waves/block, grid = (n,h)x2 ----------------
// Wave-slot s = (g&1)*4 + wave owns the balanced causal tile pair {s, 15-s}
// (work (s+1)+(16-s) = 17 units for every slot). Each tile = 16 Q-rows vs tokens 0..(a+1)*16.
// V is read pre-transposed from global Vt[n][h][d][tok] (written by gemm8) — no LDS staging,
// no block barrier. LDS = 4 per-wave P/O tiles only (33792 B) -> 4 blocks/CU by LDS.
__global__ __launch_bounds__(256, 3) void attn(const u16* __restrict__ Q, const u16* __restrict__ K,
                                               const u16* __restrict__ Vt, u16* __restrict__ O) {
  __shared__ u16 pl[4 * 16 * 264];    // per-wave P / O staging: [wave][16 rows][256(+pad) cols]
  const int g = blockIdx.x;           // 2048 = (n*16+h)*2 + j
  const int nh = g >> 1, j = g & 1;
  const int n = nh >> 4, h = nh & 15;
  const size_t base = (size_t)n * BS * D_MODEL + (size_t)h * DH;
  const u16* Qb = Q + base;
  const u16* Kb = K + base;
  const u16* Vb = Vt + (size_t)nh * (64 * 256);   // [d][tok], contiguous per (n,h)
  u16* Ob = O + base;
  const int t = threadIdx.x, wave = t >> 6, lane = t & 63, l15 = lane & 15, q4 = lane >> 4;
  const int slot = j * 4 + wave;
  u16* pw = pl + wave * 16 * 264;

#pragma unroll 1
  for (int pi = 0; pi < 2; ++pi) {
    const int a = pi ? (15 - slot) : slot;   // causal tile index, wave-uniform
    const int r0 = a * 16;

    s16x8 aq[2];
#pragma unroll
    for (int kk = 0; kk < 2; ++kk)
      aq[kk] = *(const s16x8*)(Qb + (size_t)(r0 + l15) * D_MODEL + kk * 32 + q4 * 8);

    f32x4 sc[16];
#pragma unroll
    for (int i = 0; i < 16; ++i) sc[i] = {0.f, 0.f, 0.f, 0.f};

    __builtin_amdgcn_s_setprio(1);      // T5: favor this wave's QK^T MFMA burst
#pragma unroll
    for (int nt = 0; nt < 16; ++nt) {
      if (nt <= a) {
#pragma unroll
        for (int kk = 0; kk < 2; ++kk) {
          s16x8 bk = *(const s16x8*)(Kb + (size_t)(nt * 16 + l15) * D_MODEL + kk * 32 + q4 * 8);
          sc[nt] = __builtin_amdgcn_mfma_f32_16x16x32_bf16(aq[kk], bk, sc[nt], 0, 0, 0);
        }
      }
    }
    __builtin_amdgcn_s_setprio(0);

    float mrow[4] = {-3e38f, -3e38f, -3e38f, -3e38f};
#pragma unroll
    for (int nt = 0; nt < 16; ++nt) {
      if (nt <= a) {
#pragma unroll
        for (int r = 0; r < 4; ++r) {
          int col = nt * 16 + l15;
          int row = r0 + q4 * 4 + r;
          float s = (col > row) ? -1.0e9f : sc[nt][r] * 0.125f;
          sc[nt][r] = s;
          mrow[r] = fmaxf(mrow[r], s);
        }
      }
    }
#pragma unroll
    for (int r = 0; r < 4; ++r)
#pragma unroll
      for (int off = 1; off < 16; off <<= 1)
        mrow[r] = fmaxf(mrow[r], __shfl_xor(mrow[r], off, 64));

    float lrow[4] = {0.f, 0.f, 0.f, 0.f};
#pragma unroll
    for (int nt = 0; nt < 16; ++nt) {
      if (nt <= a) {
#pragma unroll
        for (int r = 0; r < 4; ++r) {
          float e = exp2f((sc[nt][r] - mrow[r]) * 1.44269504f);
          sc[nt][r] = e;
          lrow[r] += e;
        }
      }
    }
#pragma unroll
    for (int r = 0; r < 4; ++r)
#pragma unroll
      for (int off = 1; off < 16; off <<= 1)
        lrow[r] += __shfl_xor(lrow[r], off, 64);

#pragma unroll
    for (int nt = 0; nt < 16; ++nt) {
      if (nt <= a) {
#pragma unroll
        for (int r = 0; r < 4; ++r)
          pw[(q4 * 4 + r) * 264 + nt * 16 + l15] = f2bf(sc[nt][r]);
      }
    }
    if ((a & 1) == 0) {                 // zero partner tile for the K=32 PV step
#pragma unroll
      for (int r = 0; r < 4; ++r)
        pw[(q4 * 4 + r) * 264 + (a + 1) * 16 + l15] = 0;
    }
    const int ktmax = (a + 2) >> 1;

    f32x4 oc[4];
#pragma unroll
    for (int i = 0; i < 4; ++i) oc[i] = {0.f, 0.f, 0.f, 0.f};
    __builtin_amdgcn_s_setprio(1);      // T5: favor this wave's PV MFMA burst
#pragma unroll
    for (int kt = 0; kt < 8; ++kt) {
      if (kt < ktmax) {
        s16x8 ap = *(const s16x8*)(pw + l15 * 264 + kt * 32 + q4 * 8);
#pragma unroll
        for (int dt = 0; dt < 4; ++dt) {
          s16x8 bv = *(const s16x8*)(Vb + (size_t)(dt * 16 + l15) * 256 + kt * 32 + q4 * 8);
          oc[dt] = __builtin_amdgcn_mfma_f32_16x16x32_bf16(ap, bv, oc[dt], 0, 0, 0);
        }
      }
    }
    __builtin_amdgcn_s_setprio(0);

    float inv[4];
#pragma unroll
    for (int r = 0; r < 4; ++r) inv[r] = 1.0f / lrow[r];

    // normalize, stage O tile (16 rows x 64 cols) in per-wave LDS, then b128 coalesced stores
#pragma unroll
    for (int dt = 0; dt < 4; ++dt)
#pragma unroll
      for (int r = 0; r < 4; ++r)
        pw[(q4 * 4 + r) * 264 + dt * 16 + l15] = f2bf(oc[dt][r] * inv[r]);
#pragma unroll
    for (int k = 0; k < 2; ++k) {
      int c2 = k * 64 + lane;
      int row = c2 >> 3, c8 = (c2 & 7) * 8;
      u16x8 v = *(const u16x8*)(pw + row * 264 + c8);
      *(u16x8*)(Ob + (size_t)(r0 + row) * D_MODEL + c8) = v;
    }
  }
}

extern "C" void kernel_launch(void* const* d_in, const int* in_sizes, int n_in,
                              void* d_out, int out_size, void* d_ws, size_t ws_size,
                              hipStream_t stream) {
  const float* x  = (const float*)d_in[0];
  const float* Wq = (const float*)d_in[1];
  const float* bq = (const float*)d_in[2];
  const float* Wk = (const float*)d_in[3];
  const float* bk = (const float*)d_in[4];
  const float* Wv = (const float*)d_in[5];
  const float* bv = (const float*)d_in[6];
  const float* Wo = (const float*)d_in[7];
  const float* bo = (const float*)d_in[8];
  float* out = (float*)d_out;

  // ws (bf16 internal): Wt 4x1M, xb 16M, Q/K 16M each, Vt 16M (V^T layout). O aliases Q.
  u16* ws = (u16*)d_ws;
  u16* Wt = ws;
  u16* Xb = ws + (size_t)4 * 1048576;
  u16* Qw = Xb + (size_t)16777216;
  u16* Kw = Qw + (size_t)16777216;
  u16* Vw = Kw + (size_t)16777216;   // holds V^T: [n][h][d][tok]
  u16* Ow = Qw;   // alias

  cast_x<<<dim3(8192), 256, 0, stream>>>(x, Xb);
  transpose_w<<<dim3(16, 16, 4), 256, 0, stream>>>(Wq, Wk, Wv, Wo, Wt);
  // QKV: M=16384, N=3072 -> 64 x 12 = 768 blocks (768 % 8 == 0)
  gemm8<0, 12><<<dim3(768), 512, 0, stream>>>(Xb, Wt, bq, bk, bv, Qw, Kw, Vw);
  attn<<<dim3(2048), 256, 0, stream>>>(Qw, Kw, Vw, Ow);
  // O-proj: M=16384, N=1024 -> 64 x 4 = 256 blocks
  gemm8<1, 4><<<dim3(256), 512, 0, stream>>>(Ow, Wt + (size_t)3 * 1048576, bo,
                                             nullptr, nullptr, out, nullptr, nullptr);
}

// Round 5
// 336.526 us; speedup vs baseline: 1.2219x; 1.2219x over previous
//
#include <hip/hip_runtime.h>
#include <cstdint>
#include <cstddef>

typedef unsigned short u16;
typedef __attribute__((ext_vector_type(8))) short s16x8;      // 8 bf16 = 4 VGPRs (MFMA A/B frag)
typedef __attribute__((ext_vector_type(4))) short s16x4;      // 4 bf16 = 2 VGPRs (16x16x16 frag)
typedef __attribute__((ext_vector_type(8))) unsigned short u16x8;
typedef __attribute__((ext_vector_type(4))) unsigned short u16x4;
typedef __attribute__((ext_vector_type(4))) float f32x4;      // MFMA C/D frag / float4 load

#define D_MODEL 1024
#define DH 64
#define BS 256
// B*S = 16384 tokens, 64 blocks of 256, 16 heads. External tensors are FLOAT32; internal bf16.

__device__ __forceinline__ u16 f2bf(float f) {
  union { float f; unsigned int i; } x; x.f = f;
  unsigned int r = x.i + 0x7fffu + ((x.i >> 16) & 1u);   // RNE
  return (u16)(r >> 16);
}

__device__ __forceinline__ void gl_lds16(const u16* g, u16* l) {
  __builtin_amdgcn_global_load_lds((const __attribute__((address_space(1))) void*)g,
                                   (__attribute__((address_space(3))) void*)l, 16, 0, 0);
}

__device__ __forceinline__ unsigned lds_off(const u16* p) {
  return (unsigned)(uintptr_t)(const __attribute__((address_space(3))) u16*)p;
}

// 16x16x16 bf16 MFMA (K=16): carried-forward gfx90a op, present in gfx950 ISA (§10).
__device__ __forceinline__ f32x4 mfma16(s16x4 a, s16x4 b, f32x4 c) {
#if __has_builtin(__builtin_amdgcn_mfma_f32_16x16x16bf16_1k)
  return __builtin_amdgcn_mfma_f32_16x16x16bf16_1k(a, b, c, 0, 0, 0);
#else
  asm("v_mfma_f32_16x16x16_bf16 %0, %1, %2, %0" : "+v"(c) : "v"(a), "v"(b));
  return c;
#endif
}

// ---------------- cast x: f32 -> bf16, 16.7M elems ----------------
__global__ __launch_bounds__(256) void cast_x(const float* __restrict__ x, u16* __restrict__ xb) {
  int i = (blockIdx.x * 256 + threadIdx.x) * 8;
  f32x4 a0 = *(const f32x4*)(x + i);
  f32x4 a1 = *(const f32x4*)(x + i + 4);
  u16x8 v;
#pragma unroll
  for (int j = 0; j < 4; ++j) { v[j] = f2bf(a0[j]); v[j + 4] = f2bf(a1[j]); }
  *(u16x8*)(xb + i) = v;
}

// ---------------- W transpose+cast: Wt[n][k] = bf16(W[k][n]) (1024x1024 f32 -> bf16, x4) ----------------
__global__ __launch_bounds__(256) void transpose_w(const float* __restrict__ w0,
                                                   const float* __restrict__ w1,
                                                   const float* __restrict__ w2,
                                                   const float* __restrict__ w3,
                                                   u16* __restrict__ out) {
  __shared__ u16 tile[64][65];
  const int z = blockIdx.z;
  const float* W = (z == 0) ? w0 : (z == 1) ? w1 : (z == 2) ? w2 : w3;
  u16* O = out + (size_t)z * (D_MODEL * D_MODEL);
  const int kb = blockIdx.y * 64, nb = blockIdx.x * 64;
  const int t = threadIdx.x;
#pragma unroll
  for (int i = 0; i < 16; ++i) {
    int e = i * 256 + t;
    int r = e >> 6, c = e & 63;
    tile[r][c] = f2bf(W[(size_t)(kb + r) * D_MODEL + nb + c]);
  }
  __syncthreads();
#pragma unroll
  for (int i = 0; i < 16; ++i) {
    int e = i * 256 + t;
    int r = e >> 6, c = e & 63;
    O[(size_t)(nb + r) * D_MODEL + kb + c] = tile[c][r];
  }
}

// ================= 256x256 8-phase GEMM (m201 template, plain HIP + asm ds_read) =================
// BM=BN=256, BK=64, 512 threads = 8 waves (2M x 4N), per-wave C = 128x64.
// LDS 128 KiB double-buffered. T2 swizzle byte ^= ((row&7)<<4), both-sides (rule #21).
// T4 counted vmcnt needs asm ds_read (invisible to alias analysis) + rule #18 fences.
// V plane (z==2) epilogue writes V^T [n][h][d][tok] so attn stages V with linear copies.

#define TIU 16384   // u16 per 256x64 buffer
#define HIU 8192    // u16 per 128x64 half-tile

__device__ __forceinline__ void stage_half(const u16* __restrict__ src, int rowG0, int k0,
                                           u16* ldst, int tid) {
#pragma unroll
  for (int i = 0; i < 2; ++i) {
    int c = i * 512 + tid;                       // linear 16B chunk in half-tile
    int cs = c ^ ((c >> 3) & 7);                 // inverse (row&7)<<4 swizzle (involution)
    gl_lds16(src + (size_t)(rowG0 + (cs >> 3)) * D_MODEL + k0 + (cs & 7) * 8,
             ldst + c * 8);
  }
}

#define NOPX ((void)0)
#define BARX() __builtin_amdgcn_s_barrier()
#define VMW(N) asm volatile("s_waitcnt vmcnt(" #N ")" ::: "memory")
#define SBAR() __builtin_amdgcn_sched_barrier(0)
#define LGK8() asm volatile("s_waitcnt lgkmcnt(8)")

// asm ds_read_b128: base VGPR (byte addr in LDS) + literal offset
#define DSR128(dst, b, off) asm volatile("ds_read_b128 %0, %1 offset:" #off : "=v"(dst) : "v"(b))

#define LDA8(P, MH) do { \
  const unsigned _o = (P) * 32768u + (MH) * 8192u; \
  DSR128(a[0][0], aK0 + _o, 0);    DSR128(a[0][1], aK1 + _o, 0); \
  DSR128(a[1][0], aK0 + _o, 2048); DSR128(a[1][1], aK1 + _o, 2048); \
  DSR128(a[2][0], aK0 + _o, 4096); DSR128(a[2][1], aK1 + _o, 4096); \
  DSR128(a[3][0], aK0 + _o, 6144); DSR128(a[3][1], aK1 + _o, 6144); \
} while (0)

#define LDB4(P, NH) do { \
  const unsigned _o = (P) * 32768u + (NH) * 4096u; \
  DSR128(b[NH][0][0], bK0 + _o, 0);    DSR128(b[NH][0][1], bK1 + _o, 0); \
  DSR128(b[NH][1][0], bK0 + _o, 2048); DSR128(b[NH][1][1], bK1 + _o, 2048); \
} while (0)

#define MF16(MH, NH) do { \
  __builtin_amdgcn_s_setprio(1); \
  _Pragma("unroll") for (int kk = 0; kk < 2; ++kk) \
  _Pragma("unroll") for (int mt = 0; mt < 4; ++mt) \
  _Pragma("unroll") for (int nt = 0; nt < 2; ++nt) \
    acc[(MH) * 4 + mt][(NH) * 2 + nt] = __builtin_amdgcn_mfma_f32_16x16x32_bf16( \
        a[mt][kk], b[NH][nt][kk], acc[(MH) * 4 + mt][(NH) * 2 + nt], 0, 0, 0); \
  __builtin_amdgcn_s_setprio(0); \
} while (0)

#define STA(T, H) stage_half(A, rowBase + (H) * 128, (T) * 64, As + ((T) & 1) * TIU + (H) * HIU, t)
#define STB(T, H) stage_half(W, colBase + (H) * 128, (T) * 64, Bs + ((T) & 1) * TIU + (H) * HIU, t)

// barrier -> drain LDS reads -> pin scheduler -> MFMA
#define PWAIT() do { BARX(); asm volatile("s_waitcnt lgkmcnt(0)"); SBAR(); } while (0)

// One K-tile = 4 phases; quadrant order (0,0),(0,1),(1,1),(1,0): B halves reload once, A once.
#define KTILE(P, S1, S2, S3, S4, WAIT) do { \
  LDA8(P, 0); LDB4(P, 0); S1; LGK8(); PWAIT();  MF16(0, 0); BARX(); \
  LDB4(P, 1);             S2; PWAIT();          MF16(0, 1); BARX(); \
  LDA8(P, 1);             S3; PWAIT();          MF16(1, 1); BARX(); \
                    S4; WAIT; BARX(); SBAR();   MF16(1, 0); BARX(); \
} while (0)

// MODE 0: fused QKV (bf16 out; Q,K linear, V transposed [n][h][d][tok]). MODE 1: O-proj (f32).
template <int MODE, int NCB>
__global__ __launch_bounds__(512, 2) void gemm8(
    const u16* __restrict__ A, const u16* __restrict__ W,
    const float* __restrict__ b0, const float* __restrict__ b1, const float* __restrict__ b2,
    void* __restrict__ o0, void* __restrict__ o1, void* __restrict__ o2) {
  __shared__ u16 As[2 * TIU];
  __shared__ u16 Bs[2 * TIU];

  // bijective XCD swizzle (nwg % 8 == 0 by construction: 768 / 256)
  const int nwg = gridDim.x;
  const int wg = blockIdx.x;
  const int swz = (wg & 7) * (nwg >> 3) + (wg >> 3);
  const int rowBase = (swz / NCB) * 256;
  const int colBase = (swz % NCB) * 256;

  const int t = threadIdx.x;
  const int wave = t >> 6, lane = t & 63, l15 = lane & 15, q4 = lane >> 4;
  const int wm = wave >> 2, wn = wave & 3;
  const int arow = wm * 128 + l15;
  const int brow = wn * 64 + l15;

  // LDS byte bases for asm ds_read (kk=0 / kk=1), swizzled column = (q4 ^ (l15&7)) << 4
  const unsigned swzc = (unsigned)((q4 ^ (l15 & 7)) << 4);
  const unsigned aK0 = lds_off(As) + (unsigned)arow * 128u + swzc;
  const unsigned aK1 = aK0 ^ 64u;
  const unsigned bK0 = lds_off(Bs) + (unsigned)brow * 128u + swzc;
  const unsigned bK1 = bK0 ^ 64u;

  f32x4 acc[8][4];
#pragma unroll
  for (int i = 0; i < 8; ++i)
#pragma unroll
    for (int j = 0; j < 4; ++j) acc[i][j] = {0.f, 0.f, 0.f, 0.f};

  s16x8 a[4][2];        // A frags: 4 m-tiles x 2 kk for current half
  s16x8 b[2][2][2];     // B frags: [nh][nt][kk], both halves live

  // Prologue: tile0 fully + 3 half-tiles of tile1 (issue order B0,B1,A0,A1 | B0,B1,A0)
  STB(0, 0); STB(0, 1); STA(0, 0); STA(0, 1);
  VMW(4);
  STB(1, 0); STB(1, 1); STA(1, 0);
  VMW(6);
  BARX();

#pragma unroll 1
  for (int tg = 0; tg < 14; tg += 2) {
    KTILE(0, STA(tg + 1, 1), STB(tg + 2, 0), STB(tg + 2, 1), STA(tg + 2, 0), VMW(6));
    KTILE(1, STA(tg + 2, 1), STB(tg + 3, 0), STB(tg + 3, 1), STA(tg + 3, 0), VMW(6));
  }
  // Tail: tile 14 finishes tile15's staging then drains; tile 15 computes only.
  KTILE(0, STA(15, 1), NOPX, NOPX, NOPX, VMW(0));
  KTILE(1, NOPX, NOPX, NOPX, NOPX, NOPX);

  // Epilogue: C/D map col = l15, row = q4*4 + r. ni INNERMOST so each row's 128B
  // line (64 cols x 2B) is written back-to-back -> no partial-line HBM double-write.
  if constexpr (MODE == 0) {
    const int z = colBase >> 10;                 // whole block is one z-plane (256 | 1024)
    const int colL = (colBase & 1023) + wn * 64;
    if (z < 2) {
      const float* bias = (z == 0) ? b0 : b1;
      u16* Out = (u16*)((z == 0) ? o0 : o1);
      float bv[4];
#pragma unroll
      for (int ni = 0; ni < 4; ++ni) bv[ni] = bias[colL + ni * 16 + l15];
#pragma unroll
      for (int mi = 0; mi < 8; ++mi) {
#pragma unroll
        for (int r = 0; r < 4; ++r) {
          size_t row = (size_t)(rowBase + wm * 128 + mi * 16 + q4 * 4 + r);
#pragma unroll
          for (int ni = 0; ni < 4; ++ni)
            Out[row * D_MODEL + colL + ni * 16 + l15] = f2bf(acc[mi][ni][r] + bv[ni]);
        }
      }
    } else {
      // V^T: Vt[((n*16+h)*64 + d)*256 + tok]; tok = rowBase..rowBase+255 (n = rowBase>>8),
      // d = (col&63), h = col>>6. Per lane: 4 consecutive tok -> one 8B u16x4 store.
      u16* Vt = (u16*)o2;
      const int nIdx = rowBase >> 8;
      float bv[4];
#pragma unroll
      for (int ni = 0; ni < 4; ++ni) bv[ni] = b2[colL + ni * 16 + l15];
#pragma unroll
      for (int mi = 0; mi < 8; ++mi) {
        const int tk = wm * 128 + mi * 16 + q4 * 4;
#pragma unroll
        for (int ni = 0; ni < 4; ++ni) {
          const int col = colL + ni * 16 + l15;
          u16x4 v4;
#pragma unroll
          for (int r = 0; r < 4; ++r) v4[r] = f2bf(acc[mi][ni][r] + bv[ni]);
          *(u16x4*)(Vt + (((size_t)nIdx * 16 + (col >> 6)) * 64 + (col & 63)) * 256 + tk) = v4;
        }
      }
    }
  } else {
    float* Out = (float*)o0;
    const int colL = colBase + wn * 64;
    float bv[4];
#pragma unroll
    for (int ni = 0; ni < 4; ++ni) bv[ni] = b0[colL + ni * 16 + l15];
#pragma unroll
    for (int mi = 0; mi < 8; ++mi) {
#pragma unroll
      for (int r = 0; r < 4; ++r) {
        size_t row = (size_t)(rowBase + wm * 128 + mi * 16 + q4 * 4 + r);
#pragma unroll
        for (int ni = 0; ni < 4; ++ni)
          Out[row * D_MODEL + colL + ni * 16 + l15] = acc[mi][ni][r] + bv[ni];
      }
    }
  }
}

// ---------------- Attention (R5): swapped-MFMA, in-register softmax, no P-LDS ----------------
// One block per (n,h): 512 thr = 8 waves, wave w owns balanced causal tile pair {w, 15-w}
// (work (w+1)+(16-w) = 17 units per wave). K staged in LDS with GEMM T2 swizzle; V^T staged
// in LDS (from pre-transposed global Vt) with 16B-granule XOR swizzle. One barrier total.
//
// Swapped QK^T: sc = mfma_16x16x32(A=K_frag, B=Q_frag) -> lane holds P[q=l15][k=nt*16+q4*4+r].
// Softmax: in-register over (nt,r) + 2 shfl_xor (16,32) across q4 groups. P converts to bf16
// s16x4 frags that feed PV's 16x16x16 B-operand DIRECTLY (layout match) — no LDS round-trip,
// no zero-fill. PV: oc = mfma16(A=V^T_frag, B=P_frag): lane holds O[q=l15][d=dt*16+q4*4+r]
// -> direct 8B u16x4 stores.
__global__ __launch_bounds__(512, 4) void attn(const u16* __restrict__ Q, const u16* __restrict__ K,
                                               const u16* __restrict__ Vt, u16* __restrict__ O) {
  __shared__ u16 Ks[256 * 64];        // K: [tok][feat], T2-swizzled (byte ^= (tok&7)<<4)
  __shared__ u16 Vs[64 * 256];        // V^T: [d][tok], 16B-granule swizzle (slot16 ^= d&7)
  const int nh = blockIdx.x;
  const int n = nh >> 4, h = nh & 15;
  const size_t base = (size_t)n * BS * D_MODEL + (size_t)h * DH;
  const u16* Qb = Q + base;
  const u16* Kb = K + base;
  const u16* Vg = Vt + (size_t)nh * (64 * 256);
  u16* Ob = O + base;
  const int t = threadIdx.x, wave = t >> 6, lane = t & 63, l15 = lane & 15, q4 = lane >> 4;

  // stage K (two 128-row half-tiles, same swizzle pair as gemm8)
  stage_half(Kb, 0, 0, Ks, t);
  stage_half(Kb, 128, 0, Ks + HIU, t);
  // stage V^T: 2048 16B chunks; dest linear, source 16B-slot XOR'd by (d&7)
#pragma unroll
  for (int i = 0; i < 4; ++i) {
    int c = i * 512 + t;
    int d = c >> 5, s = c & 31;
    gl_lds16(Vg + d * 256 + (s ^ (d & 7)) * 8, Vs + c * 8);
  }
  __syncthreads();                    // drains vmcnt (compiler-inserted) + barrier

  const int kswz = ((q4 << 3) ^ ((l15 & 7) << 3));   // swizzled K col (u16), kk adds ^32
  const int vswz = (l15 & 7) << 3;                   // V^T tok-offset XOR (u16)

#pragma unroll 1
  for (int pi = 0; pi < 2; ++pi) {
    const int a = pi ? (15 - wave) : wave;  // causal tile index, wave-uniform
    const int r0 = a * 16;
    const int qg = r0 + l15;                // this lane's global q row

    s16x8 aq[2];
#pragma unroll
    for (int kk = 0; kk < 2; ++kk)
      aq[kk] = *(const s16x8*)(Qb + (size_t)qg * D_MODEL + kk * 32 + q4 * 8);

    f32x4 sc[16];
#pragma unroll
    for (int i = 0; i < 16; ++i) sc[i] = {0.f, 0.f, 0.f, 0.f};

    __builtin_amdgcn_s_setprio(1);
#pragma unroll
    for (int nt = 0; nt < 16; ++nt) {
      if (nt <= a) {
#pragma unroll
        for (int kk = 0; kk < 2; ++kk) {
          s16x8 ak = *(const s16x8*)(Ks + (nt * 16 + l15) * 64 + (kswz ^ (kk << 5)));
          sc[nt] = __builtin_amdgcn_mfma_f32_16x16x32_bf16(ak, aq[kk], sc[nt], 0, 0, 0);
        }
      }
    }
    __builtin_amdgcn_s_setprio(0);

    // mask + row max (q = l15 fixed; k spans nt, q4, r)
    float m = -3e38f;
#pragma unroll
    for (int nt = 0; nt < 16; ++nt) {
      if (nt <= a) {
#pragma unroll
        for (int r = 0; r < 4; ++r) {
          int kg = nt * 16 + q4 * 4 + r;
          float s = (kg > qg) ? -1.0e9f : sc[nt][r] * 0.125f;
          sc[nt][r] = s;
          m = fmaxf(m, s);
        }
      }
    }
    m = fmaxf(m, __shfl_xor(m, 16, 64));
    m = fmaxf(m, __shfl_xor(m, 32, 64));

    // exp + row sum + pack P to bf16 PV-frags (B-operand of 16x16x16: k = q4*4 + r)
    float l = 0.f;
    s16x4 pa[16];
#pragma unroll
    for (int nt = 0; nt < 16; ++nt) {
      if (nt <= a) {
        s16x4 p;
#pragma unroll
        for (int r = 0; r < 4; ++r) {
          float e = exp2f((sc[nt][r] - m) * 1.44269504f);
          l += e;
          p[r] = (short)f2bf(e);
        }
        pa[nt] = p;
      }
    }
    l += __shfl_xor(l, 16, 64);
    l += __shfl_xor(l, 32, 64);

    // PV: per token-tile nt, per d-tile dt: A = V^T[d=dt*16+l15][tok nt*16+q4*4..+3] (8B LDS)
    f32x4 oc[4];
#pragma unroll
    for (int i = 0; i < 4; ++i) oc[i] = {0.f, 0.f, 0.f, 0.f};
    __builtin_amdgcn_s_setprio(1);
#pragma unroll
    for (int nt = 0; nt < 16; ++nt) {
      if (nt <= a) {
#pragma unroll
        for (int dt = 0; dt < 4; ++dt) {
          s16x4 av = *(const s16x4*)(Vs + (dt * 16 + l15) * 256 + ((nt * 16 + q4 * 4) ^ vswz));
          oc[dt] = mfma16(av, pa[nt], oc[dt]);
        }
      }
    }
    __builtin_amdgcn_s_setprio(0);

    // store: lane holds O[q=l15][d = dt*16 + q4*4 + r] -> 8B u16x4 per dt
    const float inv = 1.0f / l;
#pragma unroll
    for (int dt = 0; dt < 4; ++dt) {
      u16x4 v;
#pragma unroll
      for (int r = 0; r < 4; ++r) v[r] = f2bf(oc[dt][r] * inv);
      *(u16x4*)(Ob + (size_t)qg * D_MODEL + dt * 16 + q4 * 4) = v;
    }
  }
}

extern "C" void kernel_launch(void* const* d_in, const int* in_sizes, int n_in,
                              void* d_out, int out_size, void* d_ws, size_t ws_size,
                              hipStream_t stream) {
  const float* x  = (const float*)d_in[0];
  const float* Wq = (const float*)d_in[1];
  const float* bq = (const float*)d_in[2];
  const float* Wk = (const float*)d_in[3];
  const float* bk = (const float*)d_in[4];
  const float* Wv = (const float*)d_in[5];
  const float* bv = (const float*)d_in[6];
  const float* Wo = (const float*)d_in[7];
  const float* bo = (const float*)d_in[8];
  float* out = (float*)d_out;

  // ws (bf16 internal): Wt 4x1M, xb 16M, Q/K 16M each, Vt 16M (V^T layout). O aliases Q.
  u16* ws = (u16*)d_ws;
  u16* Wt = ws;
  u16* Xb = ws + (size_t)4 * 1048576;
  u16* Qw = Xb + (size_t)16777216;
  u16* Kw = Qw + (size_t)16777216;
  u16* Vw = Kw + (size_t)16777216;   // holds V^T: [n][h][d][tok]
  u16* Ow = Qw;   // alias

  cast_x<<<dim3(8192), 256, 0, stream>>>(x, Xb);
  transpose_w<<<dim3(16, 16, 4), 256, 0, stream>>>(Wq, Wk, Wv, Wo, Wt);
  // QKV: M=16384, N=3072 -> 64 x 12 = 768 blocks (768 % 8 == 0)
  gemm8<0, 12><<<dim3(768), 512, 0, stream>>>(Xb, Wt, bq, bk, bv, Qw, Kw, Vw);
  attn<<<dim3(1024), 512, 0, stream>>>(Qw, Kw, Vw, Ow);
  // O-proj: M=16384, N=1024 -> 64 x 4 = 256 blocks
  gemm8<1, 4><<<dim3(256), 512, 0, stream>>>(Ow, Wt + (size_t)3 * 1048576, bo,
                                             nullptr, nullptr, out, nullptr, nullptr);
}